// Round 16
// baseline (67.909 us; speedup 1.0000x reference)
//
#include <hip/hip_runtime.h>

// CP-rank-32: out[i,j,k] = sum_r W0[i,r]*W1[j,r]*W2[k,r]; out 256x256x1024 fp32 (268MB).
// Ladder: R8 73 / R12 67.5 / R13 66.4 / R15 66.4 (write-front coherence flat).
// R16: FUSE precompute_c away. Grid-stride (stride 768 == 0 mod 256) => j is
// block-invariant => fold W1[j,r] into w regs once per block: w'[r] = W2T[r,k]*W1[j,r].
// Per row: 32 s_load W0[i,r] (32KB table, cache-resident) + 64 pk_fma + 1 dwordx4 store.
// Reassociation W0*(W1*W2): error ~1e-12 vs 2.2e-8 abs threshold (output ~2e-6). Safe.

constexpr int I_DIM  = 256;
constexpr int J_DIM  = 256;
constexpr int K_DIM  = 1024;
constexpr int RNK    = 32;
constexpr int TOT_ROWS = I_DIM * J_DIM;   // 65536 output rows of 4 KB
constexpr int GRID     = 768;             // 3 blocks/CU; 768 % 256 == 0 (j invariant!)

typedef float f32x2 __attribute__((ext_vector_type(2)));
typedef float f32x4 __attribute__((ext_vector_type(4)));

#if defined(__has_builtin)
#  if __has_builtin(__builtin_elementwise_fma)
#    define PK_FMA(a, b, c) __builtin_elementwise_fma((a), (b), (c))
#  endif
#endif

__device__ __forceinline__ f32x2 fma2(f32x2 a, f32x2 b, f32x2 c) {
#ifdef PK_FMA
    return PK_FMA(a, b, c);
#else
    f32x2 r;
    r.x = fmaf(a.x, b.x, c.x);
    r.y = fmaf(a.y, b.y, c.y);
    return r;
#endif
}

// W2 (1024x32) -> W2T (32x1024): w loads coalesced in k.
__global__ void transpose_w2(const float* __restrict__ W2, float* __restrict__ W2T) {
    int idx = blockIdx.x * 256 + threadIdx.x;   // 0 .. 32767
    int r = idx >> 10;
    int k = idx & (K_DIM - 1);
    W2T[r * K_DIM + k] = W2[k * RNK + r];
}

// Grid-stride over output rows (row = i*256+j). j = blockIdx&255 is invariant ->
// W1 folded into w registers once. Per row: s_load W0 row, pk-FMA, one dwordx4 store.
__global__ __launch_bounds__(256, 3) void cp_recon_fw(const float* __restrict__ W0,
                                                      const float* __restrict__ W1,
                                                      const float* __restrict__ W2T,
                                                      float* __restrict__ out) {
    const int k = threadIdx.x * 4;
    const int j = blockIdx.x & (J_DIM - 1);

    // w'[r] = W2T[r, k..k+3] * W1[j,r]  — 128 VGPRs, computed once per block.
    f32x2 wlo[RNK], whi[RNK];
#pragma unroll
    for (int r = 0; r < RNK; ++r) {
        f32x4 t = *reinterpret_cast<const f32x4*>(&W2T[r * K_DIM + k]);
        float u = W1[j * RNK + r];            // uniform
        f32x2 uv = {u, u};
        wlo[r] = t.lo * uv;
        whi[r] = t.hi * uv;
    }

#pragma unroll 2
    for (int row = blockIdx.x; row < TOT_ROWS; row += GRID) {
        const int i = row >> 8;
        const float* __restrict__ c0 = W0 + (size_t)i * RNK;  // uniform -> s_load (32KB table)
        f32x2 a0 = {0.f, 0.f}, a1 = {0.f, 0.f};
#pragma unroll
        for (int r = 0; r < RNK; ++r) {
            float s = c0[r];
            f32x2 sv = {s, s};
            a0 = fma2(sv, wlo[r], a0);
            a1 = fma2(sv, whi[r], a1);
        }
        f32x4 t;
        t.lo = a0;
        t.hi = a1;
        *reinterpret_cast<f32x4*>(out + (size_t)row * K_DIM + k) = t;  // plain dwordx4
    }
}

// ---- Fallback (no ws): direct W2 reads, LDS-c, JT=8 ----
constexpr int JT = 8;
__global__ __launch_bounds__(256, 4) void cp_recon_d(const float* __restrict__ W0,
                                                     const float* __restrict__ W1,
                                                     const float* __restrict__ W2,
                                                     float* __restrict__ out) {
    __shared__ __align__(16) float c[JT][RNK];
    const int i     = blockIdx.x >> 5;
    const int jbase = (blockIdx.x & 31) * JT;
    const int tid   = threadIdx.x;

    if (tid < JT * RNK) {
        int jj = tid >> 5;
        int r  = tid & 31;
        c[jj][r] = W0[i * RNK + r] * W1[(jbase + jj) * RNK + r];
    }
    __syncthreads();

    const int k = tid * 4;
    float4 acc[JT];
#pragma unroll
    for (int jj = 0; jj < JT; ++jj) acc[jj] = make_float4(0.f, 0.f, 0.f, 0.f);

    for (int rc = 0; rc < RNK; rc += 4) {
        float4 row[4];
#pragma unroll
        for (int q = 0; q < 4; ++q)
            row[q] = *reinterpret_cast<const float4*>(&W2[(k + q) * RNK + rc]);
#pragma unroll
        for (int jj = 0; jj < JT; ++jj) {
            float4 c4 = *reinterpret_cast<const float4*>(&c[jj][rc]);
            acc[jj].x = fmaf(c4.x, row[0].x, fmaf(c4.y, row[0].y, fmaf(c4.z, row[0].z, fmaf(c4.w, row[0].w, acc[jj].x))));
            acc[jj].y = fmaf(c4.x, row[1].x, fmaf(c4.y, row[1].y, fmaf(c4.z, row[1].z, fmaf(c4.w, row[1].w, acc[jj].y))));
            acc[jj].z = fmaf(c4.x, row[2].x, fmaf(c4.y, row[2].y, fmaf(c4.z, row[2].z, fmaf(c4.w, row[2].w, acc[jj].z))));
            acc[jj].w = fmaf(c4.x, row[3].x, fmaf(c4.y, row[3].y, fmaf(c4.z, row[3].z, fmaf(c4.w, row[3].w, acc[jj].w))));
        }
    }
#pragma unroll
    for (int jj = 0; jj < JT; ++jj) {
        int o = (i * J_DIM + jbase + jj) * K_DIM + k;
        *reinterpret_cast<float4*>(&out[o]) = acc[jj];
    }
}

extern "C" void kernel_launch(void* const* d_in, const int* in_sizes, int n_in,
                              void* d_out, int out_size, void* d_ws, size_t ws_size,
                              hipStream_t stream) {
    const float* W0 = (const float*)d_in[0];
    const float* W1 = (const float*)d_in[1];
    const float* W2 = (const float*)d_in[2];
    float* out = (float*)d_out;

    const size_t w2t_bytes = (size_t)RNK * K_DIM * sizeof(float);  // 128 KB

    if (ws_size >= w2t_bytes) {
        float* W2T = (float*)d_ws;
        transpose_w2<<<(RNK * K_DIM) / 256, 256, 0, stream>>>(W2, W2T);
        cp_recon_fw<<<GRID, 256, 0, stream>>>(W0, W1, W2T, out);
    } else {
        cp_recon_d<<<I_DIM * (J_DIM / JT), 256, 0, stream>>>(W0, W1, W2, out);
    }
}

// Round 17
// 66.328 us; speedup vs baseline: 1.0238x; 1.0238x over previous
//
#include <hip/hip_runtime.h>

// CP-rank-32: out[i,j,k] = sum_r W0[i,r]*W1[j,r]*W2[k,r]; out 256x256x1024 fp32 (268MB).
// FINAL (R15 structure, best verified 66.4us): 3-kernel pipeline.
//   1) transpose_w2: W2 -> W2T (32x1024) for k-coalesced register loads.
//   2) precompute_c: C[i,j,r] = W0[i,r]*W1[j,r] (8 MB workspace).
//   3) cp_recon_gs: grid-stride over 4KB output rows; resident blocks write ADJACENT
//      rows (coherent multi-MB write front); thread = one k-float4; w[32] in 128 VGPR
//      loaded once; c via block-uniform s_load (lgkm path, store queue undisturbed);
//      2x v_pk_fma_f32 per r; one plain dwordx4 store per row.
// Ladder: R3 80(NT cap) R8 73(plain f2) R12 67.5(4KB rows) R13/R15 66.4 (best).
// Nulls: occupancy 4->6 flat, LDS-c worse, NT worse, fusion worse, 1MB sweeps worse,
// dword stores pathological. Effective 4.4 TB/s computed-write wall across 5 structures.
// Per-element chain r=0..31 sequential fused -> bit-exact vs reference (absmax 0.0).

constexpr int I_DIM  = 256;
constexpr int J_DIM  = 256;
constexpr int K_DIM  = 1024;
constexpr int RNK    = 32;
constexpr int TOT_ROWS = I_DIM * J_DIM;   // 65536 output rows of 4 KB
constexpr int GRID     = 768;             // 3 blocks/CU, all co-resident

typedef float f32x2 __attribute__((ext_vector_type(2)));
typedef float f32x4 __attribute__((ext_vector_type(4)));

#if defined(__has_builtin)
#  if __has_builtin(__builtin_elementwise_fma)
#    define PK_FMA(a, b, c) __builtin_elementwise_fma((a), (b), (c))
#  endif
#endif

__device__ __forceinline__ f32x2 fma2(f32x2 a, f32x2 b, f32x2 c) {
#ifdef PK_FMA
    return PK_FMA(a, b, c);
#else
    f32x2 r;
    r.x = fmaf(a.x, b.x, c.x);
    r.y = fmaf(a.y, b.y, c.y);
    return r;
#endif
}

// W2 (1024x32) -> W2T (32x1024): w loads coalesced in k.
__global__ void transpose_w2(const float* __restrict__ W2, float* __restrict__ W2T) {
    int idx = blockIdx.x * 256 + threadIdx.x;   // 0 .. 32767
    int r = idx >> 10;
    int k = idx & (K_DIM - 1);
    W2T[r * K_DIM + k] = W2[k * RNK + r];
}

// C[row][r] = W0[row>>8, r] * W1[row&255, r]   (8 MB; row = i*256+j)
__global__ void precompute_c(const float* __restrict__ W0, const float* __restrict__ W1,
                             float* __restrict__ C) {
    int idx = blockIdx.x * 256 + threadIdx.x;
    int r = idx & 31;
    int j = (idx >> 5) & 255;
    int i = idx >> 13;
    C[idx] = W0[i * RNK + r] * W1[j * RNK + r];
}

// Grid-stride over output rows: resident blocks write ADJACENT 4KB rows each step.
// Thread: one k-float4. Per row: 32 s_load c + 64 v_pk_fma_f32 + 1 dwordx4 store.
__global__ __launch_bounds__(256, 3) void cp_recon_gs(const float* __restrict__ C,
                                                      const float* __restrict__ W2T,
                                                      float* __restrict__ out) {
    const int k = threadIdx.x * 4;

    // Rank-32 W2T slice, split into lo/hi f32x2 pairs: 128 VGPRs, loaded once.
    f32x2 wlo[RNK], whi[RNK];
#pragma unroll
    for (int r = 0; r < RNK; ++r) {
        f32x4 t = *reinterpret_cast<const f32x4*>(&W2T[r * K_DIM + k]);
        wlo[r] = t.lo;
        whi[r] = t.hi;
    }

#pragma unroll 2
    for (int row = blockIdx.x; row < TOT_ROWS; row += GRID) {
        const float* __restrict__ cj = C + (size_t)row * RNK;  // block-uniform -> s_load
        f32x2 a0 = {0.f, 0.f}, a1 = {0.f, 0.f};
#pragma unroll
        for (int r = 0; r < RNK; ++r) {
            float s = cj[r];
            f32x2 sv = {s, s};
            a0 = fma2(sv, wlo[r], a0);
            a1 = fma2(sv, whi[r], a1);
        }
        f32x4 t;
        t.lo = a0;
        t.hi = a1;
        *reinterpret_cast<f32x4*>(out + (size_t)row * K_DIM + k) = t;  // plain dwordx4
    }
}

// ---- Fallback (no ws): direct W2 reads, LDS-c, JT=8 ----
constexpr int JT = 8;
__global__ __launch_bounds__(256, 4) void cp_recon_d(const float* __restrict__ W0,
                                                     const float* __restrict__ W1,
                                                     const float* __restrict__ W2,
                                                     float* __restrict__ out) {
    __shared__ __align__(16) float c[JT][RNK];
    const int i     = blockIdx.x >> 5;
    const int jbase = (blockIdx.x & 31) * JT;
    const int tid   = threadIdx.x;

    if (tid < JT * RNK) {
        int jj = tid >> 5;
        int r  = tid & 31;
        c[jj][r] = W0[i * RNK + r] * W1[(jbase + jj) * RNK + r];
    }
    __syncthreads();

    const int k = tid * 4;
    float4 acc[JT];
#pragma unroll
    for (int jj = 0; jj < JT; ++jj) acc[jj] = make_float4(0.f, 0.f, 0.f, 0.f);

    for (int rc = 0; rc < RNK; rc += 4) {
        float4 row[4];
#pragma unroll
        for (int q = 0; q < 4; ++q)
            row[q] = *reinterpret_cast<const float4*>(&W2[(k + q) * RNK + rc]);
#pragma unroll
        for (int jj = 0; jj < JT; ++jj) {
            float4 c4 = *reinterpret_cast<const float4*>(&c[jj][rc]);
            acc[jj].x = fmaf(c4.x, row[0].x, fmaf(c4.y, row[0].y, fmaf(c4.z, row[0].z, fmaf(c4.w, row[0].w, acc[jj].x))));
            acc[jj].y = fmaf(c4.x, row[1].x, fmaf(c4.y, row[1].y, fmaf(c4.z, row[1].z, fmaf(c4.w, row[1].w, acc[jj].y))));
            acc[jj].z = fmaf(c4.x, row[2].x, fmaf(c4.y, row[2].y, fmaf(c4.z, row[2].z, fmaf(c4.w, row[2].w, acc[jj].z))));
            acc[jj].w = fmaf(c4.x, row[3].x, fmaf(c4.y, row[3].y, fmaf(c4.z, row[3].z, fmaf(c4.w, row[3].w, acc[jj].w))));
        }
    }
#pragma unroll
    for (int jj = 0; jj < JT; ++jj) {
        int o = (i * J_DIM + jbase + jj) * K_DIM + k;
        *reinterpret_cast<float4*>(&out[o]) = acc[jj];
    }
}

extern "C" void kernel_launch(void* const* d_in, const int* in_sizes, int n_in,
                              void* d_out, int out_size, void* d_ws, size_t ws_size,
                              hipStream_t stream) {
    const float* W0 = (const float*)d_in[0];
    const float* W1 = (const float*)d_in[1];
    const float* W2 = (const float*)d_in[2];
    float* out = (float*)d_out;

    const size_t w2t_bytes = (size_t)RNK * K_DIM * sizeof(float);          // 128 KB
    const size_t c_bytes   = (size_t)I_DIM * J_DIM * RNK * sizeof(float);  // 8 MB

    if (ws_size >= w2t_bytes + c_bytes) {
        float* W2T  = (float*)d_ws;
        float* Cbuf = (float*)((char*)d_ws + w2t_bytes);
        transpose_w2<<<(RNK * K_DIM) / 256, 256, 0, stream>>>(W2, W2T);
        precompute_c<<<(I_DIM * J_DIM * RNK) / 256, 256, 0, stream>>>(W0, W1, Cbuf);
        cp_recon_gs<<<GRID, 256, 0, stream>>>(Cbuf, W2T, out);
    } else {
        cp_recon_d<<<I_DIM * (J_DIM / JT), 256, 0, stream>>>(W0, W1, W2, out);
    }
}